// Round 5
// baseline (389.865 us; speedup 1.0000x reference)
//
#include <hip/hip_runtime.h>
#include <math.h>

#define HIDDEN 1024
#define NF4 256          // float4 per row
#define NEXP 64
#define ROWS 32
#define TOPK 4
#define INNER 8
#define TOTAL 8
#define TB 4             // tokens per block, phase 1 (256 blocks -> 1/CU)
#define G 8              // pairs per block, phase 2 (~550 working blocks)
#define MAXCH 20         // chunk cap: 160 pairs/expert (mean 64, sigma ~8)
#define PADR 257         // padded x-row stride in float4 (breaks bank aliasing)

__device__ __forceinline__ float dot4(float4 a, float4 b) {
    return a.x * b.x + a.y * b.y + a.z * b.z + a.w * b.w;
}

// ---------------- phase 1: router + scatter ----------------
// lane -> (expert row, token): E = w*16 + (lane&15), token tg = lane>>4.
// Each lane computes the FULL 1024-dot for (E, tg); 4 lanes/row issue identical
// weight addresses (HW-merged). Ping-pong b0/b1 keeps 16 loads in flight.
__global__ __launch_bounds__(256, 4) void p1_router(
    const float* __restrict__ x, const float* __restrict__ rw,
    int* __restrict__ count, int* __restrict__ tok_list,
    float* __restrict__ w_arr)
{
    __shared__ float4 sx[TB * PADR];        // ~16.4 KB
    __shared__ float red[TB][NEXP + 1];
    __shared__ int   s_sel[TOPK * TB];

    const int t = threadIdx.x, lane = t & 63, w = t >> 6;
    const int rsub = lane & 15, tg = lane >> 4;
    const int E = w * 16 + rsub;
    const int tok0 = blockIdx.x * TB;

    {   // stage TB x-rows, coalesced 16 B/lane
        const float4* xs = (const float4*)(x + (size_t)tok0 * HIDDEN);
        for (int idx = t; idx < TB * NF4; idx += 256) {
            const int row = idx >> 8, col = idx & 255;
            sx[row * PADR + col] = xs[row * NF4 + col];
        }
    }
    __syncthreads();

    const float4* wp = (const float4*)(rw + (size_t)E * HIDDEN);
    const float4* xb = sx + tg * PADR;

    float acc = 0.f;
    float4 b0[8], b1[8];
    #pragma unroll
    for (int u = 0; u < 8; ++u) b0[u] = wp[u];
    #pragma unroll
    for (int u = 0; u < 8; ++u) b1[u] = wp[8 + u];

    for (int kb = 0; kb < 32; kb += 2) {
        #pragma unroll
        for (int u = 0; u < 8; ++u) acc += dot4(b0[u], xb[kb * 8 + u]);
        const int n0 = (kb + 2 < 32) ? (kb + 2) : kb;       // clamped re-load on tail
        #pragma unroll
        for (int u = 0; u < 8; ++u) b0[u] = wp[n0 * 8 + u];
        #pragma unroll
        for (int u = 0; u < 8; ++u) acc += dot4(b1[u], xb[(kb + 1) * 8 + u]);
        const int n1 = (kb + 3 < 32) ? (kb + 3) : (kb + 1);
        #pragma unroll
        for (int u = 0; u < 8; ++u) b1[u] = wp[n1 * 8 + u];
    }

    red[tg][E] = acc;
    __syncthreads();

    if (t < TB) {
        const int token = tok0 + t;
        float vals[TOPK]; int sel[TOPK];
        for (int k = 0; k < TOPK; ++k) {
            float best = -INFINITY; int bi = 0;
            for (int e = 0; e < NEXP; ++e) {
                float v = red[t][e];
                if (v > best) { best = v; bi = e; }   // ties -> lowest index
            }
            red[t][bi] = -INFINITY;
            sel[k] = bi; vals[k] = best;
        }
        const float m = vals[0];
        float ex[TOPK], s = 0.f;
        for (int k = 0; k < TOPK; ++k) { ex[k] = expf(vals[k] - m); s += ex[k]; }
        const float inv = 1.f / s;
        for (int k = 0; k < TOPK; ++k) {
            w_arr[token * TOPK + k] = ex[k] * inv;
            int pos = atomicAdd(&count[sel[k]], 1);
            tok_list[sel[k] * 1024 + pos] = (token << 2) | k;
        }
        (void)s_sel;
    }
}

// ---------------- phase 2: expert matmuls + inner top-k ----------------
// lane -> (row, token-pair): R = w*16 + (lane&15), tokens {2tg, 2tg+1}.
// Full 1024-dot per lane per token; weight row shared 4-way (merged loads).
__global__ __launch_bounds__(256, 4) void p2_experts(
    const float* __restrict__ x,
    const float* __restrict__ wg, const float* __restrict__ wu,
    const int* __restrict__ count, const int* __restrict__ tok_list,
    int* __restrict__ ids_buf)
{
    __shared__ float4 sx[G * PADR];          // ~32.9 KB
    __shared__ float  sred[G][NEXP + 1];     // [token][row 0..63]
    __shared__ float  sscore[G][ROWS];
    __shared__ int    s_entry[G];

    const int e = blockIdx.x, c0 = blockIdx.y;
    const int n = count[e];
    const int i0 = c0 * G;
    if (i0 >= n) return;
    const int T = (n - i0 < G) ? (n - i0) : G;

    const int t = threadIdx.x, lane = t & 63, w = t >> 6;
    const int rsub = lane & 15, tg = lane >> 4;
    const int R = w * 16 + rsub;              // 0..31 gate rows, 32..63 up rows
    const int tA = 2 * tg, tB = 2 * tg + 1;

    if (t < G)
        s_entry[t] = tok_list[e * 1024 + i0 + ((t < T) ? t : 0)];  // clamp -> dup work
    __syncthreads();

    {   // stage G token rows, coalesced
        for (int idx = t; idx < G * NF4; idx += 256) {
            const int row = idx >> 8, col = idx & 255;
            sx[row * PADR + col] =
                ((const float4*)(x + (size_t)(s_entry[row] >> 2) * HIDDEN))[col];
        }
    }
    __syncthreads();

    const float* wrow = (R < ROWS)
        ? wg + ((size_t)e * ROWS + R) * HIDDEN
        : wu + ((size_t)e * ROWS + (R - ROWS)) * HIDDEN;
    const float4* wp = (const float4*)wrow;
    const float4* xA = sx + tA * PADR;
    const float4* xB = sx + tB * PADR;

    float acc0 = 0.f, acc1 = 0.f;
    float4 b0[8], b1[8];
    #pragma unroll
    for (int u = 0; u < 8; ++u) b0[u] = wp[u];
    #pragma unroll
    for (int u = 0; u < 8; ++u) b1[u] = wp[8 + u];

    for (int kb = 0; kb < 32; kb += 2) {
        #pragma unroll
        for (int u = 0; u < 8; ++u) {
            acc0 += dot4(b0[u], xA[kb * 8 + u]);
            acc1 += dot4(b0[u], xB[kb * 8 + u]);
        }
        const int n0 = (kb + 2 < 32) ? (kb + 2) : kb;
        #pragma unroll
        for (int u = 0; u < 8; ++u) b0[u] = wp[n0 * 8 + u];
        #pragma unroll
        for (int u = 0; u < 8; ++u) {
            acc0 += dot4(b1[u], xA[(kb + 1) * 8 + u]);
            acc1 += dot4(b1[u], xB[(kb + 1) * 8 + u]);
        }
        const int n1 = (kb + 3 < 32) ? (kb + 3) : (kb + 1);
        #pragma unroll
        for (int u = 0; u < 8; ++u) b1[u] = wp[n1 * 8 + u];
    }

    sred[tA][R] = acc0;
    sred[tB][R] = acc1;
    __syncthreads();

    {   // silu-gate-abs: t covers 8 tok x 32 rows exactly
        const int tok = t >> 5, rr = t & 31;
        const float g = sred[tok][rr], u = sred[tok][rr + 32];
        sscore[tok][rr] = fabsf(u * (g / (1.f + expf(-g))));
    }
    __syncthreads();

    if (t < T) {
        const int entry = s_entry[t], token = entry >> 2, slot = entry & 3;
        float inner[INNER];
        #pragma unroll
        for (int i = 0; i < INNER; ++i)
            inner[i] = 0.25f * (sscore[t][4*i] + sscore[t][4*i+1]
                              + sscore[t][4*i+2] + sscore[t][4*i+3]);
        const int kk  = (slot == 0) ? 3 : ((slot == 3) ? 1 : 2);
        const int off = (slot == 0) ? 0 : ((slot == 1) ? 3 : ((slot == 2) ? 5 : 7));
        for (int k = 0; k < kk; ++k) {
            float best = -INFINITY; int bi = 0;
            #pragma unroll
            for (int i = 0; i < INNER; ++i)
                if (inner[i] > best) { best = inner[i]; bi = i; }
            inner[bi] = -INFINITY;
            ids_buf[token * TOTAL + off + k] = e * INNER + bi;
        }
    }
}

// ---------------- phase 3: assemble outputs ----------------
__global__ __launch_bounds__(256) void p3_assemble(
    const int* __restrict__ ids_buf, const float* __restrict__ w_arr,
    float* __restrict__ out, int bs)
{
    const int token = blockIdx.x * 256 + threadIdx.x;
    if (token >= bs) return;

    int ids[TOTAL];
    #pragma unroll
    for (int i = 0; i < TOTAL; ++i) ids[i] = ids_buf[token * TOTAL + i];
    for (int i = 1; i < TOTAL; ++i) {            // insertion sort, descending
        int v = ids[i]; int j = i - 1;
        while (j >= 0 && ids[j] < v) { ids[j+1] = ids[j]; --j; }
        ids[j+1] = v;
    }
    const float w0 = w_arr[token*4+0], w1 = w_arr[token*4+1];
    const float w2 = w_arr[token*4+2], w3 = w_arr[token*4+3];
    const float ws[TOTAL] = {w0, w0, w0, w1, w1, w2, w2, w3};  // already descending

    float* oid = out + (size_t)token * TOTAL;
    float* ow  = out + (size_t)bs * TOTAL + (size_t)token * TOTAL;
    #pragma unroll
    for (int i = 0; i < TOTAL; ++i) { oid[i] = (float)ids[i]; ow[i] = ws[i]; }
}

extern "C" void kernel_launch(void* const* d_in, const int* in_sizes, int n_in,
                              void* d_out, int out_size, void* d_ws, size_t ws_size,
                              hipStream_t stream) {
    const float* x  = (const float*)d_in[0];
    const float* rw = (const float*)d_in[1];
    const float* wg = (const float*)d_in[2];
    const float* wu = (const float*)d_in[3];
    float* out = (float*)d_out;
    const int bs = in_sizes[0] / HIDDEN;   // 1024

    // workspace: count[64] | tok_list[64*1024] | w_arr[bs*4] | ids_buf[bs*8]
    int*   count    = (int*)d_ws;
    int*   tok_list = count + 64;
    float* w_arr    = (float*)(tok_list + 64 * 1024);
    int*   ids_buf  = (int*)(w_arr + (size_t)bs * TOPK);

    hipMemsetAsync(count, 0, 64 * sizeof(int), stream);
    hipLaunchKernelGGL(p1_router, dim3(bs / TB), dim3(256), 0, stream,
                       x, rw, count, tok_list, w_arr);
    hipLaunchKernelGGL(p2_experts, dim3(NEXP, MAXCH), dim3(256), 0, stream,
                       x, wg, wu, count, tok_list, ids_buf);
    hipLaunchKernelGGL(p3_assemble, dim3((bs + 255) / 256), dim3(256), 0, stream,
                       ids_buf, w_arr, out, bs);
}

// Round 6
// 121.891 us; speedup vs baseline: 3.1985x; 3.1985x over previous
//
#include <hip/hip_runtime.h>
#include <math.h>

#define HIDDEN 1024
#define NF4 256          // float4 per row
#define NEXP 64
#define ROWS 32
#define TOPK 4
#define INNER 8
#define TOTAL 8
#define TB 4             // tokens per block, phase 1 (256 blocks)
#define G 8              // pairs per block, phase 2
#define MAXCH 20         // cap 160 pairs/expert (proven sufficient in round 5)

__device__ __forceinline__ float dot4(float4 a, float4 b) {
    return a.x * b.x + a.y * b.y + a.z * b.z + a.w * b.w;
}

// ---------------- phase 1: router + scatter ----------------
// 256 threads = 16 groups(g) x 16 lanes(j). Lane owns expert rows
// {g,g+16,g+32,g+48}, dim chunk c=j+16k. Each x LDS read feeds 4 dot4s
// (LDS/VALU balanced); weight loads are 16-lane coalesced 256B runs.
__global__ __launch_bounds__(256) void p1_router(
    const float* __restrict__ x, const float* __restrict__ rw,
    int* __restrict__ count, int* __restrict__ tok_list,
    float* __restrict__ w_arr)
{
    __shared__ float4 sx[TB * NF4];      // 16 KB
    __shared__ float  red[TB][NEXP];

    const int t = threadIdx.x;
    const int g = t >> 4, j = t & 15;
    const int tok0 = blockIdx.x * TB;

    {   // stage TB x rows, coalesced 16 B/lane
        const float4* xs = (const float4*)(x + (size_t)tok0 * HIDDEN);
        #pragma unroll
        for (int i = 0; i < TB; ++i) sx[i * NF4 + t] = xs[i * NF4 + t];
    }
    __syncthreads();

    const float4* wp[4];
    #pragma unroll
    for (int m = 0; m < 4; ++m)
        wp[m] = (const float4*)(rw + (size_t)(g + 16 * m) * HIDDEN);

    float acc[4][TB];
    #pragma unroll
    for (int m = 0; m < 4; ++m)
        #pragma unroll
        for (int tk = 0; tk < TB; ++tk) acc[m][tk] = 0.f;

    #pragma unroll 2
    for (int k = 0; k < 16; ++k) {
        const int c = j + 16 * k;
        float4 wf[4];                          // small batch -> loads in flight
        #pragma unroll
        for (int m = 0; m < 4; ++m) wf[m] = wp[m][c];
        #pragma unroll
        for (int tk = 0; tk < TB; ++tk) {
            float4 xb = sx[tk * NF4 + c];      // 16 consec addrs, 2-way alias: free
            #pragma unroll
            for (int m = 0; m < 4; ++m) acc[m][tk] += dot4(wf[m], xb);
        }
    }

    #pragma unroll
    for (int m = 0; m < 4; ++m)
        #pragma unroll
        for (int tk = 0; tk < TB; ++tk) {
            float v = acc[m][tk];
            v += __shfl_xor(v, 1); v += __shfl_xor(v, 2);
            v += __shfl_xor(v, 4); v += __shfl_xor(v, 8);
            acc[m][tk] = v;
        }
    if (j == 0)
        #pragma unroll
        for (int m = 0; m < 4; ++m)
            #pragma unroll
            for (int tk = 0; tk < TB; ++tk)
                red[tk][g + 16 * m] = acc[m][tk];
    __syncthreads();

    if (t < TB) {
        const int token = tok0 + t;
        float vals[TOPK]; int sel[TOPK];
        for (int k = 0; k < TOPK; ++k) {
            float best = -INFINITY; int bi = 0;
            for (int e = 0; e < NEXP; ++e) {
                float v = red[t][e];
                if (v > best) { best = v; bi = e; }   // ties -> lowest index
            }
            red[t][bi] = -INFINITY;
            sel[k] = bi; vals[k] = best;
        }
        const float m = vals[0];
        float ex[TOPK], s = 0.f;
        for (int k = 0; k < TOPK; ++k) { ex[k] = expf(vals[k] - m); s += ex[k]; }
        const float inv = 1.f / s;
        for (int k = 0; k < TOPK; ++k) {
            w_arr[token * TOPK + k] = ex[k] * inv;
            int pos = atomicAdd(&count[sel[k]], 1);
            tok_list[sel[k] * 1024 + pos] = (token << 2) | k;
        }
    }
}

// ---------------- phase 2: expert matmuls + inner top-k ----------------
// Same 4-rows-per-lane mapping over the 64 rows (32 gate + 32 up), G=8 tokens.
__global__ __launch_bounds__(256) void p2_experts(
    const float* __restrict__ x,
    const float* __restrict__ wg, const float* __restrict__ wu,
    const int* __restrict__ count, const int* __restrict__ tok_list,
    int* __restrict__ ids_buf)
{
    __shared__ float4 sx[G * NF4];           // 32 KB
    __shared__ float  sred[G][NEXP];         // [token][row 0..63]
    __shared__ float  sscore[G][ROWS];
    __shared__ int    s_entry[G];

    const int e = blockIdx.x, c0 = blockIdx.y;
    const int n = count[e];
    const int i0 = c0 * G;
    if (i0 >= n) return;
    const int T = (n - i0 < G) ? (n - i0) : G;

    const int t = threadIdx.x;
    const int g = t >> 4, j = t & 15;

    if (t < G)
        s_entry[t] = tok_list[e * 1024 + i0 + ((t < T) ? t : 0)];  // clamp -> dup work
    __syncthreads();

    {   // stage G token rows, coalesced
        #pragma unroll
        for (int i = 0; i < G; ++i)
            sx[i * NF4 + t] =
                ((const float4*)(x + (size_t)(s_entry[i] >> 2) * HIDDEN))[t];
    }
    __syncthreads();

    const float4* wp[4];
    #pragma unroll
    for (int m = 0; m < 4; ++m) {
        const int R = g + 16 * m;            // 0..31 gate rows, 32..63 up rows
        wp[m] = (const float4*)((R < ROWS)
            ? wg + ((size_t)e * ROWS + R) * HIDDEN
            : wu + ((size_t)e * ROWS + (R - ROWS)) * HIDDEN);
    }

    float acc[4][G];
    #pragma unroll
    for (int m = 0; m < 4; ++m)
        #pragma unroll
        for (int tk = 0; tk < G; ++tk) acc[m][tk] = 0.f;

    #pragma unroll 2
    for (int k = 0; k < 16; ++k) {
        const int c = j + 16 * k;
        float4 wf[4];
        #pragma unroll
        for (int m = 0; m < 4; ++m) wf[m] = wp[m][c];
        #pragma unroll
        for (int tk = 0; tk < G; ++tk) {
            float4 xb = sx[tk * NF4 + c];
            #pragma unroll
            for (int m = 0; m < 4; ++m) acc[m][tk] += dot4(wf[m], xb);
        }
    }

    #pragma unroll
    for (int m = 0; m < 4; ++m)
        #pragma unroll
        for (int tk = 0; tk < G; ++tk) {
            float v = acc[m][tk];
            v += __shfl_xor(v, 1); v += __shfl_xor(v, 2);
            v += __shfl_xor(v, 4); v += __shfl_xor(v, 8);
            acc[m][tk] = v;
        }
    if (j == 0)
        #pragma unroll
        for (int m = 0; m < 4; ++m)
            #pragma unroll
            for (int tk = 0; tk < G; ++tk)
                sred[tk][g + 16 * m] = acc[m][tk];
    __syncthreads();

    {   // silu-gate-abs: 256 threads cover 8 tok x 32 rows exactly
        const int tok = t >> 5, rr = t & 31;
        const float gg = sred[tok][rr], uu = sred[tok][rr + 32];
        sscore[tok][rr] = fabsf(uu * (gg / (1.f + expf(-gg))));
    }
    __syncthreads();

    if (t < T) {
        const int entry = s_entry[t], token = entry >> 2, slot = entry & 3;
        float inner[INNER];
        #pragma unroll
        for (int i = 0; i < INNER; ++i)
            inner[i] = 0.25f * (sscore[t][4*i] + sscore[t][4*i+1]
                              + sscore[t][4*i+2] + sscore[t][4*i+3]);
        const int kk  = (slot == 0) ? 3 : ((slot == 3) ? 1 : 2);
        const int off = (slot == 0) ? 0 : ((slot == 1) ? 3 : ((slot == 2) ? 5 : 7));
        for (int k = 0; k < kk; ++k) {
            float best = -INFINITY; int bi = 0;
            #pragma unroll
            for (int i = 0; i < INNER; ++i)
                if (inner[i] > best) { best = inner[i]; bi = i; }
            inner[bi] = -INFINITY;
            ids_buf[token * TOTAL + off + k] = e * INNER + bi;
        }
    }
}

// ---------------- phase 3: assemble outputs ----------------
__global__ __launch_bounds__(256) void p3_assemble(
    const int* __restrict__ ids_buf, const float* __restrict__ w_arr,
    float* __restrict__ out, int bs)
{
    const int token = blockIdx.x * 256 + threadIdx.x;
    if (token >= bs) return;

    int ids[TOTAL];
    #pragma unroll
    for (int i = 0; i < TOTAL; ++i) ids[i] = ids_buf[token * TOTAL + i];
    for (int i = 1; i < TOTAL; ++i) {            // insertion sort, descending
        int v = ids[i]; int j = i - 1;
        while (j >= 0 && ids[j] < v) { ids[j+1] = ids[j]; --j; }
        ids[j+1] = v;
    }
    const float w0 = w_arr[token*4+0], w1 = w_arr[token*4+1];
    const float w2 = w_arr[token*4+2], w3 = w_arr[token*4+3];
    const float ws[TOTAL] = {w0, w0, w0, w1, w1, w2, w2, w3};  // already descending

    float* oid = out + (size_t)token * TOTAL;
    float* ow  = out + (size_t)bs * TOTAL + (size_t)token * TOTAL;
    #pragma unroll
    for (int i = 0; i < TOTAL; ++i) { oid[i] = (float)ids[i]; ow[i] = ws[i]; }
}

extern "C" void kernel_launch(void* const* d_in, const int* in_sizes, int n_in,
                              void* d_out, int out_size, void* d_ws, size_t ws_size,
                              hipStream_t stream) {
    const float* x  = (const float*)d_in[0];
    const float* rw = (const float*)d_in[1];
    const float* wg = (const float*)d_in[2];
    const float* wu = (const float*)d_in[3];
    float* out = (float*)d_out;
    const int bs = in_sizes[0] / HIDDEN;   // 1024

    // workspace: count[64] | tok_list[64*1024] | w_arr[bs*4] | ids_buf[bs*8]
    int*   count    = (int*)d_ws;
    int*   tok_list = count + 64;
    float* w_arr    = (float*)(tok_list + 64 * 1024);
    int*   ids_buf  = (int*)(w_arr + (size_t)bs * TOPK);

    hipMemsetAsync(count, 0, 64 * sizeof(int), stream);
    hipLaunchKernelGGL(p1_router, dim3(bs / TB), dim3(256), 0, stream,
                       x, rw, count, tok_list, w_arr);
    hipLaunchKernelGGL(p2_experts, dim3(NEXP, MAXCH), dim3(256), 0, stream,
                       x, wg, wu, count, tok_list, ids_buf);
    hipLaunchKernelGGL(p3_assemble, dim3((bs + 255) / 256), dim3(256), 0, stream,
                       ids_buf, w_arr, out, bs);
}